// Round 6
// baseline (82.390 us; speedup 1.0000x reference)
//
#include <hip/hip_runtime.h>

#define NN   1024
#define NBLK 256

struct SharedState {
    float xL[4][128];        // layer-1 input rows
    float s1L[4][64];        // self-linear, layer 1
    float s2L[4][64];        // self-linear, layer 2
    float aggL[4][128];      // neighbor-max aggregate
    float hL[4][128];        // normalized hidden rows
    float lp[2][4][192];     // k-split GEMV partials (reused by all GEMVs)
    float redL[4][2];        // norm reduction
    unsigned long long masksL[4][16];
    int pfxL[4][16];
    int cntL[4];
    int nbrL[4][NN];         // neighbor lists: built once, used both layers
};

// Manual grid barrier. Graph-replay-safe (no runtime machinery). Deadlock-free
// by capacity: LDS 31.5KB (<=5 blk/CU) and VGPR<=128 (2 blk/CU) -> 512 slots
// >= 256 blocks, all resident at dispatch. Fused spin -> fails, never hangs.
__device__ __forceinline__ void gbar(int* cnt, int* gen) {
    __syncthreads();
    if (threadIdx.x == 0) {
        const int g = __hip_atomic_load(gen, __ATOMIC_RELAXED,
                                        __HIP_MEMORY_SCOPE_AGENT);
        __threadfence();  // release: write back my XCD's L2 to coherent L3
        if (__hip_atomic_fetch_add(cnt, 1, __ATOMIC_ACQ_REL,
                                   __HIP_MEMORY_SCOPE_AGENT) == NBLK - 1) {
            __hip_atomic_store(cnt, 0, __ATOMIC_RELAXED,
                               __HIP_MEMORY_SCOPE_AGENT);
            __hip_atomic_fetch_add(gen, 1, __ATOMIC_RELEASE,
                                   __HIP_MEMORY_SCOPE_AGENT);
        } else {
            int spins = 0;
            while (__hip_atomic_load(gen, __ATOMIC_ACQUIRE,
                                     __HIP_MEMORY_SCOPE_AGENT) == g) {
                __builtin_amdgcn_s_sleep(1);
                if (++spins > 10000000) break;  // ~0.5s fuse: fail with data
            }
        }
        __threadfence();  // acquire: invalidate L1/L2 before cross-block reads
    }
    __syncthreads();
}

// 4 rows x 192 outputs, 2-way k-split; relu(in@Wp+bp)->global, in@Ws+bs->LDS
__device__ __forceinline__ void lin_block(
    const float (&in)[4][128],
    const float* __restrict__ Wp, const float* __restrict__ bp,
    const float* __restrict__ Ws, const float* __restrict__ bs,
    float* __restrict__ pooledG, float (&sL)[4][64],
    float (&lp)[2][4][192], int v0, int tid)
{
    if (tid < 384) {
        const int kh = (tid >= 192) ? 1 : 0;
        const int j = tid - kh * 192;
        const float* w; int ld;
        if (j < 128) { w = Wp + j;         ld = 128; }
        else         { w = Ws + (j - 128); ld = 64;  }
        const int k0 = kh * 64;
        float a0 = 0.f, a1 = 0.f, a2 = 0.f, a3 = 0.f;
        #pragma unroll 4
        for (int k = 0; k < 64; ++k) {
            const float wv = w[(k0 + k) * ld];
            a0 += in[0][k0 + k] * wv;  a1 += in[1][k0 + k] * wv;
            a2 += in[2][k0 + k] * wv;  a3 += in[3][k0 + k] * wv;
        }
        lp[kh][0][j] = a0; lp[kh][1][j] = a1; lp[kh][2][j] = a2; lp[kh][3][j] = a3;
    }
    __syncthreads();
    if (tid < 192) {
        #pragma unroll
        for (int r = 0; r < 4; ++r) {
            const float t = lp[0][r][tid] + lp[1][r][tid];
            if (tid < 128) pooledG[(v0 + r) * 128 + tid] = fmaxf(t + bp[tid], 0.f);
            else           sL[r][tid - 128] = t + bs[tid - 128];
        }
    }
    __syncthreads();
}

// each 128-thread group owns one row: independent 4-way-unrolled gather-max
__device__ __forceinline__ void gather_rows(
    const float* __restrict__ src, const int (&nbrL)[4][NN],
    const int (&cntL)[4], float (&aggL)[4][128], int tid)
{
    const int d = tid & 127, r = tid >> 7;
    const int n = cntL[r];
    const int* nb = nbrL[r];
    float a0 = -1e30f, a1 = -1e30f, a2 = -1e30f, a3 = -1e30f;
    int p = 0;
    for (; p + 3 < n; p += 4) {
        a0 = fmaxf(a0, src[nb[p]     * 128 + d]);
        a1 = fmaxf(a1, src[nb[p + 1] * 128 + d]);
        a2 = fmaxf(a2, src[nb[p + 2] * 128 + d]);
        a3 = fmaxf(a3, src[nb[p + 3] * 128 + d]);
    }
    for (; p < n; ++p) a0 = fmaxf(a0, src[nb[p] * 128 + d]);
    const float m = fmaxf(fmaxf(a0, a1), fmaxf(a2, a3));
    aggL[r][d] = (m <= -5e29f) ? 0.f : m;  // isolated -> 0
    __syncthreads();
}

// agg@Wn+bn (all 512 threads: 4 rows x 64 j x 2 k-halves), concat sL, relu,
// row-L2-normalize -> hL
__device__ __forceinline__ void wn_norm(
    const float* __restrict__ Wn, const float* __restrict__ bn,
    const float (&aggL)[4][128], const float (&sL)[4][64],
    float (&lp)[2][4][192], float (&redL)[4][2], float (&hL)[4][128],
    int tid)
{
    {
        const int j  = tid & 63;
        const int r  = (tid >> 6) & 3;
        const int kh = tid >> 8;
        const int k0 = kh * 64;
        float a = 0.f;
        #pragma unroll 4
        for (int k = 0; k < 64; ++k) a += aggL[r][k0 + k] * Wn[(k0 + k) * 64 + j];
        lp[kh][r][j] = a;
    }
    __syncthreads();
    const int d = tid & 127, r = tid >> 7;
    float val = (d < 64) ? sL[r][d]
                         : (bn[d - 64] + lp[0][r][d - 64] + lp[1][r][d - 64]);
    val = fmaxf(val, 0.f);
    float ss = val * val;
    #pragma unroll
    for (int off = 32; off >= 1; off >>= 1) ss += __shfl_xor(ss, off, 64);
    if ((tid & 63) == 0) redL[r][(tid >> 6) & 1] = ss;
    __syncthreads();
    const float nrm = fmaxf(sqrtf(redL[r][0] + redL[r][1]), 1e-12f);
    hL[r][d] = val / nrm;
    __syncthreads();
}

__global__ __launch_bounds__(512, 4) void fused_sage(
    const float* __restrict__ x, const int* __restrict__ A,
    const float* __restrict__ Wp1, const float* __restrict__ bp1,
    const float* __restrict__ Ws1, const float* __restrict__ bs1,
    const float* __restrict__ Wn1, const float* __restrict__ bn1,
    const float* __restrict__ Wp2, const float* __restrict__ bp2,
    const float* __restrict__ Ws2, const float* __restrict__ bs2,
    const float* __restrict__ Wn2, const float* __restrict__ bn2,
    const float* __restrict__ Wh, const float* __restrict__ bh,
    float* __restrict__ out, float* __restrict__ pooled1,
    float* __restrict__ pooled2, int* __restrict__ bar)
{
    __shared__ SharedState S;
    const int tid  = threadIdx.x;
    const int lane = tid & 63;
    const int wv   = tid >> 6;     // wave 0..7
    const int v0   = blockIdx.x * 4;
    int* bcnt = bar;
    int* bgen = bar + 32;          // separate cache line

    // ---- Phase A: layer-1 linears ----
    S.xL[tid >> 7][tid & 127] = x[v0 * 128 + tid];
    __syncthreads();
    lin_block(S.xL, Wp1, bp1, Ws1, bs1, pooled1, S.s1L, S.lp, v0, tid);

    // ---- Neighbor lists via ballot+prefix, built ONCE for both layers ----
    {
        const int r = wv >> 1;
        const int* Arow = A + (v0 + r) * NN;
        #pragma unroll
        for (int c8 = 0; c8 < 8; ++c8) {
            const int c = (wv & 1) * 8 + c8;
            const unsigned long long m = __ballot(Arow[c * 64 + lane] != 0);
            if (lane == 0) S.masksL[r][c] = m;
        }
    }
    __syncthreads();
    if (tid < 4) {
        int off = 0;
        #pragma unroll
        for (int c = 0; c < 16; ++c) {
            S.pfxL[tid][c] = off;
            off += __popcll(S.masksL[tid][c]);
        }
        S.cntL[tid] = off;
    }
    __syncthreads();
    {
        const int r = wv >> 1;
        #pragma unroll
        for (int c8 = 0; c8 < 8; ++c8) {
            const int c = (wv & 1) * 8 + c8;
            const unsigned long long m = S.masksL[r][c];
            if ((m >> lane) & 1ull) {
                const int pos = S.pfxL[r][c] +
                                __popcll(m & ((1ull << lane) - 1ull));
                S.nbrL[r][pos] = c * 64 + lane;
            }
        }
    }

    gbar(bcnt, bgen);  // pooled1 visible everywhere

    // ---- Phase B: layer-1 aggregate+norm, fused layer-2 linears ----
    gather_rows(pooled1, S.nbrL, S.cntL, S.aggL, tid);
    wn_norm(Wn1, bn1, S.aggL, S.s1L, S.lp, S.redL, S.hL, tid);
    lin_block(S.hL, Wp2, bp2, Ws2, bs2, pooled2, S.s2L, S.lp, v0, tid);

    gbar(bcnt, bgen);  // pooled2 visible everywhere

    // ---- Phase C: layer-2 aggregate+norm + classifier head ----
    gather_rows(pooled2, S.nbrL, S.cntL, S.aggL, tid);
    wn_norm(Wn2, bn2, S.aggL, S.s2L, S.lp, S.redL, S.hL, tid);

    if (tid < 320) {  // 4 rows x 40 outputs x 2 k-halves
        const int kh  = (tid >= 160) ? 1 : 0;
        const int idx = tid - kh * 160;
        const int r   = idx / 40;
        const int j   = idx - r * 40;
        const int k0  = kh * 64;
        float a = 0.f;
        #pragma unroll 4
        for (int k = 0; k < 64; ++k) a += S.hL[r][k0 + k] * Wh[(k0 + k) * 40 + j];
        S.lp[kh][r][j] = a;
    }
    __syncthreads();
    if (tid < 160) {
        const int r = tid / 40;
        const int j = tid - r * 40;
        out[(v0 + r) * 40 + j] = bh[j] + S.lp[0][r][j] + S.lp[1][r][j];
    }
}

extern "C" void kernel_launch(void* const* d_in, const int* in_sizes, int n_in,
                              void* d_out, int out_size, void* d_ws, size_t ws_size,
                              hipStream_t stream) {
    const float* x   = (const float*)d_in[0];
    const int*   A   = (const int*)  d_in[1];
    const float* Wp1 = (const float*)d_in[2];
    const float* bp1 = (const float*)d_in[3];
    const float* Ws1 = (const float*)d_in[4];
    const float* bs1 = (const float*)d_in[5];
    const float* Wn1 = (const float*)d_in[6];
    const float* bn1 = (const float*)d_in[7];
    const float* Wp2 = (const float*)d_in[8];
    const float* bp2 = (const float*)d_in[9];
    const float* Ws2 = (const float*)d_in[10];
    const float* bs2 = (const float*)d_in[11];
    const float* Wn2 = (const float*)d_in[12];
    const float* bn2 = (const float*)d_in[13];
    const float* Wh  = (const float*)d_in[14];
    const float* bh  = (const float*)d_in[15];
    float* out = (float*)d_out;

    char* ws = (char*)d_ws;
    float* pooled1 = (float*)(ws);                  // 512 KB
    float* pooled2 = (float*)(ws + (512u << 10));   // 512 KB
    int*   bar     = (int*)  (ws + (1024u << 10));  // 256 B barrier state

    hipMemsetAsync(bar, 0, 256, stream);  // cnt=gen=0 every call (deterministic)

    fused_sage<<<dim3(NBLK), dim3(512), 0, stream>>>(
        x, A, Wp1, bp1, Ws1, bs1, Wn1, bn1,
        Wp2, bp2, Ws2, bs2, Wn2, bn2, Wh, bh,
        out, pooled1, pooled2, bar);
}

// Round 9
// 29.711 us; speedup vs baseline: 2.7730x; 2.7730x over previous
//
#include <hip/hip_runtime.h>

#define NN 1024

// ---------- K1: first linear + neighbor-list build (A read ONCE) ----------
// 256 blocks x 512 threads, 4 nodes/block.
// threads 0..383: GEMV partials for pooled1/s1 (192 outputs x 2 k-halves)
// all 8 waves:    ballot-scan A rows -> compacted neighbor lists -> global
__global__ __launch_bounds__(512) void lin_build(
    const float* __restrict__ X, const float* __restrict__ Wp,
    const float* __restrict__ bp, const float* __restrict__ Ws,
    const float* __restrict__ bs, const int* __restrict__ A,
    float* __restrict__ pooled, float* __restrict__ sbuf,
    int* __restrict__ nbrG, int* __restrict__ cntG)
{
    __shared__ float xL[4][128];
    __shared__ float lp[2][4][192];
    __shared__ unsigned long long masksL[4][16];
    __shared__ int pfxL[4][16];

    const int tid  = threadIdx.x;
    const int lane = tid & 63;
    const int wv   = tid >> 6;       // wave 0..7
    const int v0   = blockIdx.x * 4;

    xL[tid >> 7][tid & 127] = X[v0 * 128 + tid];
    __syncthreads();

    // GEMV partials (threads 0..383) -- independent of the A-scan below
    if (tid < 384) {
        const int kh = (tid >= 192) ? 1 : 0;
        const int j = tid - kh * 192;
        const float* w; int ld;
        if (j < 128) { w = Wp + j;         ld = 128; }
        else         { w = Ws + (j - 128); ld = 64;  }
        const int k0 = kh * 64;
        float a0 = 0.f, a1 = 0.f, a2 = 0.f, a3 = 0.f;
        #pragma unroll 4
        for (int k = 0; k < 64; ++k) {
            const float wvv = w[(k0 + k) * ld];
            a0 += xL[0][k0 + k] * wvv;  a1 += xL[1][k0 + k] * wvv;
            a2 += xL[2][k0 + k] * wvv;  a3 += xL[3][k0 + k] * wvv;
        }
        lp[kh][0][j] = a0; lp[kh][1][j] = a1; lp[kh][2][j] = a2; lp[kh][3][j] = a3;
    }
    // A-scan: wave wv handles row (wv>>1), chunks (wv&1)*8 .. +8
    {
        const int r = wv >> 1;
        const int* Arow = A + (v0 + r) * NN;
        #pragma unroll
        for (int c8 = 0; c8 < 8; ++c8) {
            const int c = (wv & 1) * 8 + c8;
            const unsigned long long m = __ballot(Arow[c * 64 + lane] != 0);
            if (lane == 0) masksL[r][c] = m;
        }
    }
    __syncthreads();

    // prefix (4 threads) + GEMV reduction/writeback (threads 0..191)
    if (tid < 4) {
        int off = 0;
        #pragma unroll
        for (int c = 0; c < 16; ++c) {
            pfxL[tid][c] = off;
            off += __popcll(masksL[tid][c]);
        }
        cntG[v0 + tid] = off;
    }
    if (tid < 192) {
        #pragma unroll
        for (int r = 0; r < 4; ++r) {
            const float t = lp[0][r][tid] + lp[1][r][tid];
            if (tid < 128) pooled[(v0 + r) * 128 + tid] = fmaxf(t + bp[tid], 0.f);
            else           sbuf[(v0 + r) * 64 + (tid - 128)] = t + bs[tid - 128];
        }
    }
    __syncthreads();

    // compaction scatter: every set bit knows its slot (deterministic)
    {
        const int r = wv >> 1;
        #pragma unroll
        for (int c8 = 0; c8 < 8; ++c8) {
            const int c = (wv & 1) * 8 + c8;
            const unsigned long long m = masksL[r][c];
            if ((m >> lane) & 1ull) {
                const int pos = pfxL[r][c] + __popcll(m & ((1ull << lane) - 1ull));
                nbrG[(v0 + r) * NN + pos] = c * 64 + lane;
            }
        }
    }
}

// ---------- K2/K3: aggregate + norm + fused next linear (or head) ----------
// One block (512 threads) per node v. Neighbor list PRELOADED from K1.
// MODE 0: writes pooled2 = relu(h@Wp2+bp2), s2 = h@Ws2+bs2
// MODE 1: Wp2:=Wh, bp2:=bh; writes outh = h@Wh+bh
template <int MODE>
__global__ __launch_bounds__(512) void agg_kernel(
    const int* __restrict__ nbrG, const int* __restrict__ cntG,
    const float* __restrict__ pooled, const float* __restrict__ sbuf,
    const float* __restrict__ Wn, const float* __restrict__ bn,
    const float* __restrict__ Wp2, const float* __restrict__ bp2,
    const float* __restrict__ Ws2, const float* __restrict__ bs2,
    float* __restrict__ out_pooled, float* __restrict__ out_s,
    float* __restrict__ outh)
{
    __shared__ int   nbr[NN];
    __shared__ float part[4][128];
    __shared__ float aggL[128];
    __shared__ float wpart[4][64];
    __shared__ float hL[128];
    __shared__ float lpart[2][192];
    __shared__ float red[2];

    const int v   = blockIdx.x;
    const int tid = threadIdx.x;

    // short front-end: count + one coalesced burst of the list into LDS
    const int n = cntG[v];
    for (int i = tid; i < n; i += 512) nbr[i] = nbrG[v * NN + i];
    __syncthreads();

    // 4-team gather-max, 4-way unrolled (4 independent loads in flight)
    const int d    = tid & 127;
    const int team = tid >> 7;
    float a0 = -1e30f, a1 = -1e30f, a2 = -1e30f, a3 = -1e30f;
    int p = team;
    for (; p + 12 < n; p += 16) {
        a0 = fmaxf(a0, pooled[nbr[p]      * 128 + d]);
        a1 = fmaxf(a1, pooled[nbr[p + 4]  * 128 + d]);
        a2 = fmaxf(a2, pooled[nbr[p + 8]  * 128 + d]);
        a3 = fmaxf(a3, pooled[nbr[p + 12] * 128 + d]);
    }
    for (; p < n; p += 4) a0 = fmaxf(a0, pooled[nbr[p] * 128 + d]);
    part[team][d] = fmaxf(fmaxf(a0, a1), fmaxf(a2, a3));
    __syncthreads();

    // combine teams; isolated nodes -> 0
    if (team == 0) {
        const float m = fmaxf(fmaxf(part[0][d], part[1][d]),
                              fmaxf(part[2][d], part[3][d]));
        aggL[d] = (m <= -5e29f) ? 0.f : m;
    }
    __syncthreads();

    // agg @ Wn with 4-way k-split (256 threads: teams x 64 outputs)
    if (d >= 64) {
        const int j = d - 64;
        const float* w = Wn + j;
        const int k0 = team * 32;
        float pv = 0.f;
        #pragma unroll 8
        for (int k = 0; k < 32; ++k) pv += aggL[k0 + k] * w[(k0 + k) * 64];
        wpart[team][j] = pv;
    }
    __syncthreads();

    // concat + relu + L2 normalize (threads 0..127)
    float val = 0.f;
    if (tid < 128) {
        if (d < 64) val = sbuf[v * 64 + d];
        else {
            const int j = d - 64;
            val = bn[j] + wpart[0][j] + wpart[1][j] + wpart[2][j] + wpart[3][j];
        }
        val = fmaxf(val, 0.f);
        float ss = val * val;
        #pragma unroll
        for (int off = 32; off >= 1; off >>= 1) ss += __shfl_xor(ss, off, 64);
        if ((tid & 63) == 0) red[tid >> 6] = ss;
    }
    __syncthreads();
    if (tid < 128) {
        const float nrm = fmaxf(sqrtf(red[0] + red[1]), 1e-12f);
        hL[tid] = val / nrm;
    }
    __syncthreads();

    // fused next-layer linear / classifier head
    if (MODE == 0) {
        if (tid < 384) {  // 192 outputs x 2 k-halves
            const int kh = (tid >= 192) ? 1 : 0;
            const int j  = tid - kh * 192;
            const float* w; int ld;
            if (j < 128) { w = Wp2 + j;         ld = 128; }
            else         { w = Ws2 + (j - 128); ld = 64;  }
            float a = 0.f;
            const int k0 = kh * 64;
            #pragma unroll 4
            for (int k = 0; k < 64; ++k) a += hL[k0 + k] * w[(k0 + k) * ld];
            lpart[kh][j] = a;
        }
        __syncthreads();
        if (tid < 192) {
            const float r = lpart[0][tid] + lpart[1][tid];
            if (tid < 128) out_pooled[v * 128 + tid] = fmaxf(r + bp2[tid], 0.f);
            else           out_s[v * 64 + (tid - 128)] = r + bs2[tid - 128];
        }
    } else {
        // head: 40 outputs x 2 k-halves (waves 0 and 4)
        if (tid < 64 || (tid >= 256 && tid < 320)) {
            const int kh = (tid >= 256) ? 1 : 0;
            const int j  = tid - kh * 256;
            if (j < 40) {
                float a = 0.f;
                const int k0 = kh * 64;
                #pragma unroll 4
                for (int k = 0; k < 64; ++k) a += hL[k0 + k] * Wp2[(k0 + k) * 40 + j];
                lpart[kh][j] = a;
            }
        }
        __syncthreads();
        if (tid < 40) outh[v * 40 + tid] = bp2[tid] + lpart[0][tid] + lpart[1][tid];
    }
}

extern "C" void kernel_launch(void* const* d_in, const int* in_sizes, int n_in,
                              void* d_out, int out_size, void* d_ws, size_t ws_size,
                              hipStream_t stream) {
    const float* x   = (const float*)d_in[0];
    const int*   A   = (const int*)  d_in[1];
    const float* Wp1 = (const float*)d_in[2];
    const float* bp1 = (const float*)d_in[3];
    const float* Ws1 = (const float*)d_in[4];
    const float* bs1 = (const float*)d_in[5];
    const float* Wn1 = (const float*)d_in[6];
    const float* bn1 = (const float*)d_in[7];
    const float* Wp2 = (const float*)d_in[8];
    const float* bp2 = (const float*)d_in[9];
    const float* Ws2 = (const float*)d_in[10];
    const float* bs2 = (const float*)d_in[11];
    const float* Wn2 = (const float*)d_in[12];
    const float* bn2 = (const float*)d_in[13];
    const float* Wh  = (const float*)d_in[14];
    const float* bh  = (const float*)d_in[15];
    float* out = (float*)d_out;

    char* ws = (char*)d_ws;
    float* pooled1 = (float*)(ws);                  // 512 KB
    float* s1      = (float*)(ws + (512u << 10));   // 256 KB
    float* pooled2 = (float*)(ws + (768u << 10));   // 512 KB
    float* s2      = (float*)(ws + (1280u << 10));  // 256 KB
    int*   nbrG    = (int*)  (ws + (1536u << 10));  // 4 MB (1024 x 1024 ints)
    int*   cntG    = (int*)  (ws + (5632u << 10));  // 4 KB

    lin_build<<<NN / 4, 512, 0, stream>>>(x, Wp1, bp1, Ws1, bs1, A,
                                          pooled1, s1, nbrG, cntG);
    agg_kernel<0><<<NN, 512, 0, stream>>>(nbrG, cntG, pooled1, s1, Wn1, bn1,
                                          Wp2, bp2, Ws2, bs2,
                                          pooled2, s2, nullptr);
    agg_kernel<1><<<NN, 512, 0, stream>>>(nbrG, cntG, pooled2, s2, Wn2, bn2,
                                          Wh, bh, nullptr, nullptr,
                                          nullptr, nullptr, out);
}

// Round 11
// 28.506 us; speedup vs baseline: 2.8902x; 1.0423x over previous
//
#include <hip/hip_runtime.h>

#define NN 1024

// ---------- K1: first linear + neighbor-list build (A read ONCE) ----------
// 256 blocks x 512 threads, 4 nodes/block.
__global__ __launch_bounds__(512) void lin_build(
    const float* __restrict__ X, const float* __restrict__ Wp,
    const float* __restrict__ bp, const float* __restrict__ Ws,
    const float* __restrict__ bs, const int* __restrict__ A,
    float* __restrict__ pooled, float* __restrict__ sbuf,
    int* __restrict__ nbrG, int* __restrict__ cntG)
{
    __shared__ float xL[4][128];
    __shared__ float lp[2][4][192];
    __shared__ unsigned long long masksL[4][16];
    __shared__ int pfxL[4][16];

    const int tid  = threadIdx.x;
    const int lane = tid & 63;
    const int wv   = tid >> 6;       // wave 0..7
    const int v0   = blockIdx.x * 4;

    xL[tid >> 7][tid & 127] = X[v0 * 128 + tid];
    __syncthreads();

    if (tid < 384) {  // GEMV partials: 192 outputs x 2 k-halves, 4 rows/thread
        const int kh = (tid >= 192) ? 1 : 0;
        const int j = tid - kh * 192;
        const float* w; int ld;
        if (j < 128) { w = Wp + j;         ld = 128; }
        else         { w = Ws + (j - 128); ld = 64;  }
        const int k0 = kh * 64;
        float a0 = 0.f, a1 = 0.f, a2 = 0.f, a3 = 0.f;
        #pragma unroll 4
        for (int k = 0; k < 64; ++k) {
            const float wvv = w[(k0 + k) * ld];
            a0 += xL[0][k0 + k] * wvv;  a1 += xL[1][k0 + k] * wvv;
            a2 += xL[2][k0 + k] * wvv;  a3 += xL[3][k0 + k] * wvv;
        }
        lp[kh][0][j] = a0; lp[kh][1][j] = a1; lp[kh][2][j] = a2; lp[kh][3][j] = a3;
    }
    {   // A-scan: wave wv -> row (wv>>1), chunks (wv&1)*8..+8
        const int r = wv >> 1;
        const int* Arow = A + (v0 + r) * NN;
        #pragma unroll
        for (int c8 = 0; c8 < 8; ++c8) {
            const int c = (wv & 1) * 8 + c8;
            const unsigned long long m = __ballot(Arow[c * 64 + lane] != 0);
            if (lane == 0) masksL[r][c] = m;
        }
    }
    __syncthreads();

    if (tid < 4) {
        int off = 0;
        #pragma unroll
        for (int c = 0; c < 16; ++c) {
            pfxL[tid][c] = off;
            off += __popcll(masksL[tid][c]);
        }
        cntG[v0 + tid] = off;
    }
    if (tid < 192) {
        #pragma unroll
        for (int r = 0; r < 4; ++r) {
            const float t = lp[0][r][tid] + lp[1][r][tid];
            if (tid < 128) pooled[(v0 + r) * 128 + tid] = fmaxf(t + bp[tid], 0.f);
            else           sbuf[(v0 + r) * 64 + (tid - 128)] = t + bs[tid - 128];
        }
    }
    __syncthreads();

    {   // compaction scatter
        const int r = wv >> 1;
        #pragma unroll
        for (int c8 = 0; c8 < 8; ++c8) {
            const int c = (wv & 1) * 8 + c8;
            const unsigned long long m = masksL[r][c];
            if ((m >> lane) & 1ull) {
                const int pos = pfxL[r][c] + __popcll(m & ((1ull << lane) - 1ull));
                nbrG[(v0 + r) * NN + pos] = c * 64 + lane;
            }
        }
    }
}

// ---------- K2/K3: TWO nodes per block; weights reused for both ----------
// 512 blocks x 512 threads (2 blocks/CU, 16 waves/CU).
// MODE 0: writes pooled2 = relu(h@Wp2+bp2), s2 = h@Ws2+bs2
// MODE 1: Wp2:=Wh, bp2:=bh; writes outh = h@Wh+bh
template <int MODE>
__global__ __launch_bounds__(512) void agg_kernel(
    const int* __restrict__ nbrG, const int* __restrict__ cntG,
    const float* __restrict__ pooled, const float* __restrict__ sbuf,
    const float* __restrict__ Wn, const float* __restrict__ bn,
    const float* __restrict__ Wp2, const float* __restrict__ bp2,
    const float* __restrict__ Ws2, const float* __restrict__ bs2,
    float* __restrict__ out_pooled, float* __restrict__ out_s,
    float* __restrict__ outh)
{
    __shared__ int   nbr[2][NN];
    __shared__ float sL[2][64];
    __shared__ float part[4][128];
    __shared__ float aggL[2][128];
    __shared__ float wq[2][8][64];   // ksplit-8 partials (Wn, and head in MODE1)
    __shared__ float hL[2][128];
    __shared__ float lp2[2][2][192]; // MODE0 lin partials [kh][node][j]
    __shared__ float red[2][2];

    const int v0  = blockIdx.x * 2;
    const int tid = threadIdx.x;

    // front-end: counts + self-linear rows + both neighbor lists
    const int n0 = cntG[v0], n1 = cntG[v0 + 1];
    if (tid < 128) sL[tid >> 6][tid & 63] = sbuf[v0 * 64 + tid];
    for (int i = tid; i < n0; i += 512) nbr[0][i] = nbrG[v0 * NN + i];
    for (int i = tid; i < n1; i += 512) nbr[1][i] = nbrG[(v0 + 1) * NN + i];
    __syncthreads();

    // gather-max: slice s=tid>>7; node r=s>>1, offset o=s&1, stride 2, 8 accs
    {
        const int d = tid & 127, s = tid >> 7;
        const int r = s >> 1, o = s & 1;
        const int n = r ? n1 : n0;
        const int* nb = nbr[r];
        float a0=-1e30f,a1=-1e30f,a2=-1e30f,a3=-1e30f,
              a4=-1e30f,a5=-1e30f,a6=-1e30f,a7=-1e30f;
        int p = o;
        for (; p + 14 < n; p += 16) {
            a0 = fmaxf(a0, pooled[nb[p]      * 128 + d]);
            a1 = fmaxf(a1, pooled[nb[p + 2]  * 128 + d]);
            a2 = fmaxf(a2, pooled[nb[p + 4]  * 128 + d]);
            a3 = fmaxf(a3, pooled[nb[p + 6]  * 128 + d]);
            a4 = fmaxf(a4, pooled[nb[p + 8]  * 128 + d]);
            a5 = fmaxf(a5, pooled[nb[p + 10] * 128 + d]);
            a6 = fmaxf(a6, pooled[nb[p + 12] * 128 + d]);
            a7 = fmaxf(a7, pooled[nb[p + 14] * 128 + d]);
        }
        for (; p < n; p += 2) a0 = fmaxf(a0, pooled[nb[p] * 128 + d]);
        a0 = fmaxf(a0, a1); a2 = fmaxf(a2, a3);
        a4 = fmaxf(a4, a5); a6 = fmaxf(a6, a7);
        part[s][d] = fmaxf(fmaxf(a0, a2), fmaxf(a4, a6));
    }
    __syncthreads();
    if (tid < 256) {  // combine slices; isolated -> 0
        const int r = tid >> 7, d = tid & 127;
        const float m = fmaxf(part[2 * r][d], part[2 * r + 1][d]);
        aggL[r][d] = (m <= -5e29f) ? 0.f : m;
    }
    __syncthreads();

    // agg @ Wn: ksplit-8 x 64 outputs = 512 tasks, BOTH nodes per thread
    {
        const int t = tid >> 6, j = tid & 63, k0 = t * 16;
        float a0 = 0.f, a1 = 0.f;
        #pragma unroll
        for (int k = 0; k < 16; ++k) {
            const float w = Wn[(k0 + k) * 64 + j];
            a0 += aggL[0][k0 + k] * w;
            a1 += aggL[1][k0 + k] * w;
        }
        wq[0][t][j] = a0; wq[1][t][j] = a1;
    }
    __syncthreads();

    // concat + relu + L2 normalize (nodes on waves 0-1 / 2-3)
    float val = 0.f;
    {
        const int r = (tid >> 7) & 1, d = tid & 127;
        if (tid < 256) {
            if (d < 64) val = sL[r][d];
            else {
                const int j = d - 64;
                float acc = bn[j];
                #pragma unroll
                for (int t = 0; t < 8; ++t) acc += wq[r][t][j];
                val = acc;
            }
            val = fmaxf(val, 0.f);
        }
        float ss = val * val;
        #pragma unroll
        for (int off = 32; off >= 1; off >>= 1) ss += __shfl_xor(ss, off, 64);
        if (tid < 256 && (tid & 63) == 0) red[r][(tid >> 6) & 1] = ss;
    }
    __syncthreads();
    if (tid < 256) {
        const int r = tid >> 7, d = tid & 127;
        const float nrm = fmaxf(sqrtf(red[r][0] + red[r][1]), 1e-12f);
        hL[r][d] = val / nrm;
    }
    __syncthreads();

    if (MODE == 0) {
        // next-layer linears: 192 outputs x 2 k-halves, both nodes per thread
        if (tid < 384) {
            const int kh = (tid >= 192) ? 1 : 0;
            const int j  = tid - kh * 192;
            const float* w; int ld;
            if (j < 128) { w = Wp2 + j;         ld = 128; }
            else         { w = Ws2 + (j - 128); ld = 64;  }
            const int k0 = kh * 64;
            float a0 = 0.f, a1 = 0.f;
            #pragma unroll 4
            for (int k = 0; k < 64; ++k) {
                const float wv = w[(k0 + k) * ld];
                a0 += hL[0][k0 + k] * wv;
                a1 += hL[1][k0 + k] * wv;
            }
            lp2[kh][0][j] = a0; lp2[kh][1][j] = a1;
        }
        __syncthreads();
        if (tid < 192) {
            #pragma unroll
            for (int r = 0; r < 2; ++r) {
                const float t = lp2[0][r][tid] + lp2[1][r][tid];
                if (tid < 128) out_pooled[(v0 + r) * 128 + tid] = fmaxf(t + bp2[tid], 0.f);
                else           out_s[(v0 + r) * 64 + (tid - 128)] = t + bs2[tid - 128];
            }
        }
    } else {
        // head: ksplit-8 x 40 outputs = 320 tasks, both nodes per thread
        if (tid < 320) {
            const int t = tid / 40, j = tid - t * 40;
            const int k0 = t * 16;
            float a0 = 0.f, a1 = 0.f;
            #pragma unroll
            for (int k = 0; k < 16; ++k) {
                const float wv = Wp2[(k0 + k) * 40 + j];  // Wp2 := Wh
                a0 += hL[0][k0 + k] * wv;
                a1 += hL[1][k0 + k] * wv;
            }
            wq[0][t][j] = a0; wq[1][t][j] = a1;
        }
        __syncthreads();
        if (tid < 80) {
            const int r = tid / 40, j = tid - r * 40;
            float acc = bp2[j];  // bh
            #pragma unroll
            for (int t = 0; t < 8; ++t) acc += wq[r][t][j];
            outh[(v0 + r) * 40 + j] = acc;
        }
    }
}

extern "C" void kernel_launch(void* const* d_in, const int* in_sizes, int n_in,
                              void* d_out, int out_size, void* d_ws, size_t ws_size,
                              hipStream_t stream) {
    const float* x   = (const float*)d_in[0];
    const int*   A   = (const int*)  d_in[1];
    const float* Wp1 = (const float*)d_in[2];
    const float* bp1 = (const float*)d_in[3];
    const float* Ws1 = (const float*)d_in[4];
    const float* bs1 = (const float*)d_in[5];
    const float* Wn1 = (const float*)d_in[6];
    const float* bn1 = (const float*)d_in[7];
    const float* Wp2 = (const float*)d_in[8];
    const float* bp2 = (const float*)d_in[9];
    const float* Ws2 = (const float*)d_in[10];
    const float* bs2 = (const float*)d_in[11];
    const float* Wn2 = (const float*)d_in[12];
    const float* bn2 = (const float*)d_in[13];
    const float* Wh  = (const float*)d_in[14];
    const float* bh  = (const float*)d_in[15];
    float* out = (float*)d_out;

    char* ws = (char*)d_ws;
    float* pooled1 = (float*)(ws);                  // 512 KB
    float* s1      = (float*)(ws + (512u << 10));   // 256 KB
    float* pooled2 = (float*)(ws + (768u << 10));   // 512 KB
    float* s2      = (float*)(ws + (1280u << 10));  // 256 KB
    int*   nbrG    = (int*)  (ws + (1536u << 10));  // 4 MB
    int*   cntG    = (int*)  (ws + (5632u << 10));  // 4 KB

    lin_build<<<NN / 4, 512, 0, stream>>>(x, Wp1, bp1, Ws1, bs1, A,
                                          pooled1, s1, nbrG, cntG);
    agg_kernel<0><<<NN / 2, 512, 0, stream>>>(nbrG, cntG, pooled1, s1, Wn1, bn1,
                                              Wp2, bp2, Ws2, bs2,
                                              pooled2, s2, nullptr);
    agg_kernel<1><<<NN / 2, 512, 0, stream>>>(nbrG, cntG, pooled2, s2, Wn2, bn2,
                                              Wh, bh, nullptr, nullptr,
                                              nullptr, nullptr, out);
}